// Round 16
// baseline (197.590 us; speedup 1.0000x reference)
//
#include <hip/hip_runtime.h>
#include <stdint.h>

typedef int i32x4 __attribute__((ext_vector_type(4)));

#define B_ 16
#define N_ 577
#define C_ 768
#define H_ 12
#define D_ 64
#define BN_ (B_ * N_)   // 9232
#define O3_ (3 * C_)    // 2304
#define NP_ 592         // padded seq length (37*16)
#define BH_ (B_ * H_)   // 192
#define NT_ 10          // 64-row tiles per head (quant_qkv + attention)
#define KT_ 12          // K=768 -> 12 K-steps of 64

typedef __attribute__((address_space(1))) const void gvoid;
typedef __attribute__((address_space(3))) void lvoid;

__device__ __forceinline__ void gload16(const void* g, void* l) {
  __builtin_amdgcn_global_load_lds((gvoid*)g, (lvoid*)l, 16, 0, 0);
}

__device__ __forceinline__ float fexp2(float x) {
  float r;
  asm("v_exp_f32 %0, %1" : "=v"(r) : "v"(x));
  return r;
}

__device__ __forceinline__ int8_t quant8(float x, float s) {
  float r = rintf(x / s);               // RNE + true divide: matches jnp exactly
  r = fminf(127.0f, fmaxf(-127.0f, r));
  return (int8_t)(int)r;
}

__device__ __forceinline__ float scale_from(const float* scal, int idx, float pre) {
  return fmaxf(pre * scal[idx] / 127.0f, 1e-8f);
}

// bijective XCD-contiguous swizzle (m204)
__device__ __forceinline__ int xcd_contig(int bid, int nwg) {
  int q = nwg >> 3, r = nwg & 7;
  int xcd = bid & 7, idx = bid >> 3;
  return xcd < r ? xcd * (q + 1) + idx : r * (q + 1) + (xcd - r) * q + idx;
}

// 4x4 lane-group transpose via shfl_xor butterfly (verified all 16 cells):
//   out pf[j]@group g == in pw[g]@group j   (same movement as the LDS round-trip)
__device__ __forceinline__ i32x4 lane_group_transpose(const unsigned pw[4], int lg) {
  unsigned u[4];
#pragma unroll
  for (int j = 0; j < 4; j++) {
    unsigned other = (unsigned)__shfl_xor((int)pw[j ^ 1], 16);
    u[j] = ((j ^ lg) & 1) ? other : pw[j];
  }
  i32x4 pf;
#pragma unroll
  for (int j = 0; j < 4; j++) {
    unsigned other = (unsigned)__shfl_xor((int)u[j ^ 2], 32);
    pf[j] = (int)(((j ^ lg) & 2) ? other : u[j]);
  }
  return pf;
}

// pack 4 dwords (value in low byte each) into one dword {b3,b2,b1,b0}
__device__ __forceinline__ unsigned pack4(unsigned e0, unsigned e1, unsigned e2, unsigned e3) {
  unsigned t01 = __builtin_amdgcn_perm(e1, e0, 0x00000400u);
  unsigned t23 = __builtin_amdgcn_perm(e3, e2, 0x00000400u);
  return __builtin_amdgcn_perm(t23, t01, 0x05040100u);
}

// ---------------- init scalar slots ----------------
// [0]=amax_x [1]=amax_qkvw [2]=amax_projw [3]=amax_q_raw [4]=amax_k [5]=amax_v
// [6]=minZ (init +inf) [7]=amax_score
__global__ void init_scal_k(float* scal) {
  int t = threadIdx.x;
  if (t < 16) scal[t] = (t == 6) ? INFINITY : 0.0f;
}

// ---------------- fused absmax over 3 tensors (2x unrolled, dual accumulators) ----
__global__ __launch_bounds__(256) void absmax3_k(
    const float4* __restrict__ p0, long n0, const float4* __restrict__ p1, long n1,
    const float4* __restrict__ p2, long n2, unsigned* __restrict__ slots) {
  const int sidx = blockIdx.y;
  const float4* p;
  long n4;
  if (sidx == 0) { p = p0; n4 = n0; }
  else if (sidx == 1) { p = p1; n4 = n1; }
  else { p = p2; n4 = n2; }
  float ma = 0.0f, mb = 0.0f;
  long stride = (long)gridDim.x * 256;
  for (long i = (long)blockIdx.x * 256 + threadIdx.x; i < n4; i += 2 * stride) {
    float4 v = p[i];
    ma = fmaxf(ma, fmaxf(fmaxf(fabsf(v.x), fabsf(v.y)), fmaxf(fabsf(v.z), fabsf(v.w))));
    long i2 = i + stride;
    if (i2 < n4) {
      float4 u = p[i2];
      mb = fmaxf(mb, fmaxf(fmaxf(fabsf(u.x), fabsf(u.y)), fmaxf(fabsf(u.z), fabsf(u.w))));
    }
  }
  float m = fmaxf(ma, mb);
#pragma unroll
  for (int off = 32; off; off >>= 1) m = fmaxf(m, __shfl_xor(m, off));
  __shared__ float rb[4];
  if ((threadIdx.x & 63) == 0) rb[threadIdx.x >> 6] = m;
  __syncthreads();
  if (threadIdx.x == 0) {
    m = fmaxf(fmaxf(rb[0], rb[1]), fmaxf(rb[2], rb[3]));
    atomicMax(slots + sidx, __float_as_uint(m));  // float>=0: uint order == float order
  }
}

// ---------------- fused quantize of 3 tensors (2x unrolled) ----------------
__global__ __launch_bounds__(256) void quant3_k(
    const float4* __restrict__ i0, char4* __restrict__ o0, long n0,
    const float4* __restrict__ i1, char4* __restrict__ o1, long n1,
    const float4* __restrict__ i2, char4* __restrict__ o2, long n2,
    const float* __restrict__ scal) {
  const int sidx = blockIdx.y;
  const float4* in;
  char4* out;
  long n4;
  if (sidx == 0) { in = i0; out = o0; n4 = n0; }
  else if (sidx == 1) { in = i1; out = o1; n4 = n1; }
  else { in = i2; out = o2; n4 = n2; }
  float s = scale_from(scal, sidx, 1.0f);
  long stride = (long)gridDim.x * 256;
  for (long i = (long)blockIdx.x * 256 + threadIdx.x; i < n4; i += 2 * stride) {
    float4 v = in[i];
    long i2 = i + stride;
    float4 u = (i2 < n4) ? in[i2] : make_float4(0, 0, 0, 0);
    char4 c;
    c.x = quant8(v.x, s); c.y = quant8(v.y, s);
    c.z = quant8(v.z, s); c.w = quant8(v.w, s);
    out[i] = c;
    if (i2 < n4) {
      char4 d;
      d.x = quant8(u.x, s); d.y = quant8(u.y, s);
      d.z = quant8(u.z, s); d.w = quant8(u.w, s);
      out[i2] = d;
    }
  }
}

// ---------------- generic quantize (score, 2x unrolled) ----------------
__global__ __launch_bounds__(256) void quant_k(const float4* __restrict__ in,
                                               char4* __restrict__ out, long n4,
                                               const float* __restrict__ scal, int sidx) {
  float s = scale_from(scal, sidx, 1.0f);
  long stride = (long)gridDim.x * 256;
  for (long i = (long)blockIdx.x * 256 + threadIdx.x; i < n4; i += 2 * stride) {
    float4 v = in[i];
    long i2 = i + stride;
    float4 u = (i2 < n4) ? in[i2] : make_float4(0, 0, 0, 0);
    char4 c;
    c.x = quant8(v.x, s); c.y = quant8(v.y, s);
    c.z = quant8(v.z, s); c.w = quant8(v.w, s);
    out[i] = c;
    if (i2 < n4) {
      char4 d;
      d.x = quant8(u.x, s); d.y = quant8(u.y, s);
      d.z = quant8(u.z, s); d.w = quant8(u.w, s);
      out[i2] = d;
    }
  }
}

// ---------------- int8 NT GEMM: C[M,N] = deq(A[M,K] @ B[N,K]^T) + bias ----------------
// 256x128 tile, 8 waves, 3-slot LDS ring, depth-2 prefetch, counted vmcnt(3),
// setprio; LDS-coalesced f32 epilogue (R12 structure, unchanged).
// MODE 0: qkv  — write C f32 + per-part (q/k/v) absmax
// MODE 1: proj — write C f32
template <int MODE>
__global__ __launch_bounds__(512) void gemm_i8_nt(
    const int8_t* __restrict__ A, const int8_t* __restrict__ Bm,
    const float* __restrict__ bias, float* __restrict__ Cc,
    const float* __restrict__ scal, int sa_idx, int sb_idx,
    int M, int N, int nyb, unsigned* __restrict__ amax_slots) {
  const int K = 768;
  __shared__ __align__(16) int8_t smem[73728];  // 3x16KB A-ring + 3x8KB B-ring
  const int t = threadIdx.x;
  const int l = t & 63, w = t >> 6;          // 8 waves
  const int wm = w >> 1, wn = w & 1;         // 4x2 wave grid -> 256x128
  const int l15 = l & 15, lg = l >> 4;
  const int lin = xcd_contig(blockIdx.x, gridDim.x);
  const int m0 = (lin / nyb) * 256, n0 = (lin % nyb) * 128;

  const int row0 = t >> 2, slot = t & 3;     // rows 0..127, 16B slot
  int ar0 = m0 + row0;        if (ar0 >= M) ar0 = M - 1;
  int ar1 = m0 + 128 + row0;  if (ar1 >= M) ar1 = M - 1;
  const int8_t* gA0 = A + (size_t)ar0 * K + slot * 16;
  const int8_t* gA1 = A + (size_t)ar1 * K + slot * 16;
  const int8_t* gB0 = Bm + (size_t)(n0 + row0) * K + slot * 16;

  auto stage = [&](int buf, int k0) {
    int8_t* la = smem + buf * 16384 + w * 1024;
    int8_t* lb = smem + 49152 + buf * 8192 + w * 1024;
    gload16(gA0 + k0, la);
    gload16(gA1 + k0, la + 8192);
    gload16(gB0 + k0, lb);
  };

  i32x4 zero = {0, 0, 0, 0};
  i32x4 acc[4][4];
#pragma unroll
  for (int i = 0; i < 4; i++)
#pragma unroll
    for (int j = 0; j < 4; j++) acc[i][j] = zero;

  stage(0, 0);
  stage(1, 64);

#pragma unroll
  for (int kt = 0; kt < KT_; kt++) {
    if (kt < KT_ - 1) asm volatile("s_waitcnt vmcnt(3)" ::: "memory");
    else              asm volatile("s_waitcnt vmcnt(0)" ::: "memory");
    __builtin_amdgcn_s_barrier();
    __builtin_amdgcn_sched_barrier(0);  // pin stage/ds_read below the barrier
    if (kt + 2 < KT_) stage((kt + 2) % 3, (kt + 2) * 64);
    const int8_t* as_ = smem + (kt % 3) * 16384;
    const int8_t* bs_ = smem + 49152 + (kt % 3) * 8192;
    i32x4 af[4], bf[4];
#pragma unroll
    for (int i = 0; i < 4; i++)
      af[i] = *(const i32x4*)(as_ + (wm * 64 + i * 16 + l15) * 64 + lg * 16);
#pragma unroll
    for (int j = 0; j < 4; j++)
      bf[j] = *(const i32x4*)(bs_ + (wn * 64 + j * 16 + l15) * 64 + lg * 16);
    __builtin_amdgcn_s_setprio(1);
#pragma unroll
    for (int i = 0; i < 4; i++)
#pragma unroll
      for (int j = 0; j < 4; j++)
        acc[i][j] = __builtin_amdgcn_mfma_i32_16x16x64_i8(af[i], bf[j], acc[i][j], 0, 0, 0);
    __builtin_amdgcn_s_setprio(0);
    asm volatile("s_waitcnt lgkmcnt(0)" ::: "memory");
    __builtin_amdgcn_sched_barrier(0);
  }

  const float ab = scale_from(scal, sa_idx, 1.0f) * scale_from(scal, sb_idx, 1.0f);
  float lmax = 0.0f;
  float* eplds = (float*)smem;  // epilogue tile: 128 rows x 132 f32 (pad)
#pragma unroll
  for (int h = 0; h < 2; h++) {
    __syncthreads();  // staging reads (h=0) / prior stores (h=1) done
    if ((wm >> 1) == h) {
      const int lrbase = (wm & 1) * 64;
#pragma unroll
      for (int i = 0; i < 4; i++) {
#pragma unroll
        for (int j = 0; j < 4; j++) {
          int lc = wn * 64 + j * 16 + l15;
          float bv = bias[n0 + lc];
#pragma unroll
          for (int r = 0; r < 4; r++) {
            int lr = lrbase + i * 16 + lg * 4 + r;
            float v = (float)acc[i][j][r] * ab + bv;
            eplds[lr * 132 + lc] = v;
            if (MODE == 0) {
              if (m0 + h * 128 + lr < M) lmax = fmaxf(lmax, fabsf(v));
            }
          }
        }
      }
    }
    __syncthreads();
#pragma unroll
    for (int it = 0; it < 8; it++) {
      int e = it * 512 + t;
      int row = e >> 5, c4 = e & 31;
      int grow = m0 + h * 128 + row;
      if (grow < M)
        *(float4*)(Cc + (size_t)grow * N + n0 + c4 * 4) =
            *(const float4*)(eplds + row * 132 + c4 * 4);
    }
  }
  if (MODE == 0) {
#pragma unroll
    for (int off = 32; off; off >>= 1) lmax = fmaxf(lmax, __shfl_xor(lmax, off));
    __shared__ float rb[8];
    if (l == 0) rb[w] = lmax;
    __syncthreads();
    if (t == 0) {
      float v = fmaxf(fmaxf(fmaxf(rb[0], rb[1]), fmaxf(rb[2], rb[3])),
                      fmaxf(fmaxf(rb[4], rb[5]), fmaxf(rb[6], rb[7])));
      atomicMax(amax_slots + (n0 / 768), __float_as_uint(v));
    }
  }
}

// ---------------- quantize qkv -> q_i8, k_i8, vT_i8 ----------------
__global__ __launch_bounds__(256) void quant_qkv_k(
    const float* __restrict__ qkv, int8_t* __restrict__ qq,
    int8_t* __restrict__ kq, int8_t* __restrict__ vT,
    const float* __restrict__ scal) {
  const int ntile = blockIdx.x, bh = blockIdx.y;
  const int b = bh / H_, h = bh % H_;
  const int t = threadIdx.x;
  const float sq = scale_from(scal, 3, 0.125f);  // q pre-scaled by D^-0.5
  const float sk = scale_from(scal, 4, 1.0f);
  const float sv = scale_from(scal, 5, 1.0f);
  __shared__ int8_t vt[64 * 68];
  const int n0 = ntile * 64;
#pragma unroll
  for (int i = 0; i < 4; i++) {
    int e = i * 256 + t;          // 0..1023 = 64 rows x 16 float4
    int nl = e >> 4, d4 = e & 15;
    int n = n0 + nl;
    float4 qv = {0, 0, 0, 0}, kv = {0, 0, 0, 0}, vv = {0, 0, 0, 0};
    if (n < N_) {
      const float* base = qkv + (size_t)(b * N_ + n) * O3_ + h * D_ + d4 * 4;
      qv = *(const float4*)(base);
      kv = *(const float4*)(base + C_);
      vv = *(const float4*)(base + 2 * C_);
    }
    char4 qb, kb, vb;
    qb.x = quant8(0.125f * qv.x, sq); qb.y = quant8(0.125f * qv.y, sq);
    qb.z = quant8(0.125f * qv.z, sq); qb.w = quant8(0.125f * qv.w, sq);
    kb.x = quant8(kv.x, sk); kb.y = quant8(kv.y, sk);
    kb.z = quant8(kv.z, sk); kb.w = quant8(kv.w, sk);
    vb.x = quant8(vv.x, sv); vb.y = quant8(vv.y, sv);
    vb.z = quant8(vv.z, sv); vb.w = quant8(vv.w, sv);
    if (n < NP_) {
      size_t o = (size_t)(bh * NP_ + n) * D_ + d4 * 4;
      *(char4*)(qq + o) = qb;
      *(char4*)(kq + o) = kb;
    }
    *(char4*)(vt + nl * 68 + d4 * 4) = vb;
  }
  __syncthreads();
#pragma unroll
  for (int i = 0; i < 16; i++) {
    int e = i * 256 + t;
    int dr = e >> 6, nn = e & 63;
    int n = n0 + nn;
    if (n < NP_) vT[(size_t)(bh * 64 + dr) * NP_ + n] = vt[nn * 68 + dr];
  }
}

// ---------------- attention pass A: per-row (max, Z) in exp2 domain ----------------
// 2 q-fragments per wave (32 rows), 2-wave/128-thread blocks, grid 1920:
// finer dispatch granularity packs the straggler tail. Per-wave work == R13.
__global__ __launch_bounds__(128) void attn_passA(
    const int8_t* __restrict__ qq, const int8_t* __restrict__ kq,
    float* __restrict__ mbuf, float* __restrict__ zbuf,
    const float* __restrict__ scal, unsigned* __restrict__ minz_slot) {
  const int lin = xcd_contig(blockIdx.x, gridDim.x);
  const int bh = lin / NT_, ntile = lin % NT_;
  const int t = threadIdx.x;
  const int l = t & 63, w = t >> 6;   // 2 waves x 32 rows
  const int l15 = l & 15, lg = l >> 4;
  const float qk2 =
      scale_from(scal, 3, 0.125f) * scale_from(scal, 4, 1.0f) * 1.4426950408889634f;
  const int nrow0 = ntile * 64 + w * 32 + l15;
  const int nrow1 = nrow0 + 16;
  const int nc0 = nrow0 < NP_ ? nrow0 : 0;
  const int nc1 = nrow1 < NP_ ? nrow1 : 0;
  const i32x4 qf0 = *(const i32x4*)(qq + ((size_t)bh * NP_ + nc0) * 64 + lg * 16);
  const i32x4 qf1 = *(const i32x4*)(qq + ((size_t)bh * NP_ + nc1) * 64 + lg * 16);
  const int8_t* kb = kq + (size_t)bh * NP_ * 64;

  i32x4 zero = {0, 0, 0, 0};
  i32x4 k0 = *(const i32x4*)(kb + (0 * 16 + l15) * 64 + lg * 16);
  i32x4 k1 = *(const i32x4*)(kb + (1 * 16 + l15) * 64 + lg * 16);
  i32x4 k2 = *(const i32x4*)(kb + (2 * 16 + l15) * 64 + lg * 16);
  i32x4 k3 = *(const i32x4*)(kb + (3 * 16 + l15) * 64 + lg * 16);

  float m2a = -INFINITY, zla = 0.0f, m2b = -INFINITY, zlb = 0.0f;
#pragma unroll
  for (int ct = 0; ct < 36; ct++) {
    i32x4 kfc = k0;
    k0 = k1; k1 = k2; k2 = k3;
    if (ct + 4 <= 36)
      k3 = *(const i32x4*)(kb + ((ct + 4) * 16 + l15) * 64 + lg * 16);
    i32x4 sc0 = __builtin_amdgcn_mfma_i32_16x16x64_i8(kfc, qf0, zero, 0, 0, 0);
    i32x4 sc1 = __builtin_amdgcn_mfma_i32_16x16x64_i8(kfc, qf1, zero, 0, 0, 0);
    {
      float s0 = (float)sc0[0] * qk2, s1 = (float)sc0[1] * qk2;
      float s2 = (float)sc0[2] * qk2, s3 = (float)sc0[3] * qk2;
      float m4 = fmaxf(fmaxf(s0, s1), fmaxf(s2, s3));
      float nm = fmaxf(m2a, m4);
      zla = zla * fexp2(m2a - nm) +
            ((fexp2(s0 - nm) + fexp2(s1 - nm)) + (fexp2(s2 - nm) + fexp2(s3 - nm)));
      m2a = nm;
    }
    {
      float s0 = (float)sc1[0] * qk2, s1 = (float)sc1[1] * qk2;
      float s2 = (float)sc1[2] * qk2, s3 = (float)sc1[3] * qk2;
      float m4 = fmaxf(fmaxf(s0, s1), fmaxf(s2, s3));
      float nm = fmaxf(m2b, m4);
      zlb = zlb * fexp2(m2b - nm) +
            ((fexp2(s0 - nm) + fexp2(s1 - nm)) + (fexp2(s2 - nm) + fexp2(s3 - nm)));
      m2b = nm;
    }
  }
  {  // ct=36 (in k0 after rotation): only col 576 valid (lg==0 && r==0)
    i32x4 sc0 = __builtin_amdgcn_mfma_i32_16x16x64_i8(k0, qf0, zero, 0, 0, 0);
    i32x4 sc1 = __builtin_amdgcn_mfma_i32_16x16x64_i8(k0, qf1, zero, 0, 0, 0);
    float sa = (lg == 0) ? (float)sc0[0] * qk2 : -INFINITY;
    float sb = (lg == 0) ? (float)sc1[0] * qk2 : -INFINITY;
    float nma = fmaxf(m2a, sa);
    zla = zla * fexp2(m2a - nma) + fexp2(sa - nma);
    m2a = nma;
    float nmb = fmaxf(m2b, sb);
    zlb = zlb * fexp2(m2b - nmb) + fexp2(sb - nmb);
    m2b = nmb;
  }
#pragma unroll
  for (int off = 16; off <= 32; off <<= 1) {
    float om = __shfl_xor(m2a, off), ol = __shfl_xor(zla, off);
    float nm = fmaxf(m2a, om);
    zla = zla * fexp2(m2a - nm) + ol * fexp2(om - nm);
    m2a = nm;
    om = __shfl_xor(m2b, off); ol = __shfl_xor(zlb, off);
    nm = fmaxf(m2b, om);
    zlb = zlb * fexp2(m2b - nm) + ol * fexp2(om - nm);
    m2b = nm;
  }
  const bool rv0 = nrow0 < N_, rv1 = nrow1 < N_;
  if (lg == 0) {
    if (rv0) {
      mbuf[(size_t)bh * NP_ + nrow0] = m2a;
      zbuf[(size_t)bh * NP_ + nrow0] = zla;
    }
    if (rv1) {
      mbuf[(size_t)bh * NP_ + nrow1] = m2b;
      zbuf[(size_t)bh * NP_ + nrow1] = zlb;
    }
  }
  float cand = INFINITY;
  if (lg == 0) {
    if (rv0) cand = zla;
    if (rv1) cand = fminf(cand, zlb);
  }
#pragma unroll
  for (int off = 32; off; off >>= 1) cand = fminf(cand, __shfl_xor(cand, off));
  __shared__ float rb[2];
  if (l == 0) rb[w] = cand;
  __syncthreads();
  if (t == 0)
    atomicMin(minz_slot, __float_as_uint(fminf(rb[0], rb[1])));
}

// ---------------- attention pass B: p = fq(softmax), score = deq(p @ v) ----------------
// 2 q-fragments per wave, 2-wave/128-thread blocks, grid 1920. Register-pipelined
// kf/vf prefetch + in-register transpose + v_perm byte packing (pure data movement).
__global__ __launch_bounds__(128) void attn_passB(
    const int8_t* __restrict__ qq, const int8_t* __restrict__ kq,
    const int8_t* __restrict__ vT, const float* __restrict__ mbuf,
    const float* __restrict__ zbuf, const float* __restrict__ scal,
    float* __restrict__ score, unsigned* __restrict__ amax_slot) {
  const int lin = xcd_contig(blockIdx.x, gridDim.x);
  const int bh = lin / NT_, ntile = lin % NT_;
  const int b = bh / H_, h = bh % H_;
  const int t = threadIdx.x;
  const int l = t & 63, w = t >> 6;   // 2 waves x 32 rows
  const int l15 = l & 15, lg = l >> 4;
  const int8_t* kb = kq + (size_t)bh * NP_ * 64;
  const int8_t* vbase = vT + (size_t)bh * 64 * NP_;

  const float qk2 =
      scale_from(scal, 3, 0.125f) * scale_from(scal, 4, 1.0f) * 1.4426950408889634f;
  const float sv = scale_from(scal, 5, 1.0f);
  const float minz = scal[6];
  const float sp = fmaxf((1.0f / minz) / 127.0f, 1e-8f);  // amax(softmax) = 1/minZ

  const int nrow0 = ntile * 64 + w * 32 + l15;
  const int nrow1 = nrow0 + 16;
  const int nc0 = nrow0 < NP_ ? nrow0 : 0;
  const int nc1 = nrow1 < NP_ ? nrow1 : 0;
  const i32x4 qf0 = *(const i32x4*)(qq + ((size_t)bh * NP_ + nc0) * 64 + lg * 16);
  const i32x4 qf1 = *(const i32x4*)(qq + ((size_t)bh * NP_ + nc1) * 64 + lg * 16);
  float crow0 = -INFINITY, crow1 = -INFINITY;
  if (nrow0 < N_)
    crow0 = -mbuf[(size_t)bh * NP_ + nrow0] - log2f(zbuf[(size_t)bh * NP_ + nrow0] * sp);
  if (nrow1 < N_)
    crow1 = -mbuf[(size_t)bh * NP_ + nrow1] - log2f(zbuf[(size_t)bh * NP_ + nrow1] * sp);

  i32x4 zero = {0, 0, 0, 0};
  i32x4 oacc0[4], oacc1[4];
#pragma unroll
  for (int j = 0; j < 4; j++) { oacc0[j] = zero; oacc1[j] = zero; }

  i32x4 kfr[4], vfr[4];
#pragma unroll
  for (int q4 = 0; q4 < 4; q4++) {
    kfr[q4] = *(const i32x4*)(kb + (q4 * 16 + l15) * 64 + lg * 16);
    vfr[q4] = *(const i32x4*)(vbase + (size_t)(q4 * 16 + l15) * NP_ + 0 * 64 + lg * 16);
  }

#pragma unroll
  for (int chunk = 0; chunk < 9; chunk++) {
    // prefetch kf AND vf for NEXT chunk (or tail) -- both a full chunk ahead
    i32x4 kfn[4], vfn[4];
    if (chunk < 8) {
#pragma unroll
      for (int q4 = 0; q4 < 4; q4++) {
        kfn[q4] = *(const i32x4*)(kb + (((chunk + 1) * 4 + q4) * 16 + l15) * 64 + lg * 16);
        vfn[q4] = *(const i32x4*)(vbase + (size_t)(q4 * 16 + l15) * NP_ +
                                  (chunk + 1) * 64 + lg * 16);
      }
    } else {
      kfn[0] = *(const i32x4*)(kb + (36 * 16 + l15) * 64 + lg * 16);
      kfn[1] = zero; kfn[2] = zero; kfn[3] = zero;
#pragma unroll
      for (int j = 0; j < 4; j++)
        vfn[j] = *(const i32x4*)(vbase + (size_t)(j * 16 + l15) * NP_ + 576);
    }
    // QK + softmax + pack for both q-groups (kf already in regs)
    unsigned pw0[4], pw1[4];
#pragma unroll
    for (int q4 = 0; q4 < 4; q4++) {
      i32x4 sc0 = __builtin_amdgcn_mfma_i32_16x16x64_i8(kfr[q4], qf0, zero, 0, 0, 0);
      i32x4 sc1 = __builtin_amdgcn_mfma_i32_16x16x64_i8(kfr[q4], qf1, zero, 0, 0, 0);
      unsigned e0[4], e1[4];
#pragma unroll
      for (int r = 0; r < 4; r++) {
        float s0 = (float)sc0[r] * qk2;
        e0[r] = (unsigned)(int)fminf(rintf(fexp2(s0 + crow0)), 127.0f);
        float s1 = (float)sc1[r] * qk2;
        e1[r] = (unsigned)(int)fminf(rintf(fexp2(s1 + crow1)), 127.0f);
      }
      pw0[q4] = pack4(e0[0], e0[1], e0[2], e0[3]);
      pw1[q4] = pack4(e1[0], e1[1], e1[2], e1[3]);
    }
    i32x4 pf0 = lane_group_transpose(pw0, lg);
    i32x4 pf1 = lane_group_transpose(pw1, lg);
#pragma unroll
    for (int j = 0; j < 4; j++) {
      oacc0[j] = __builtin_amdgcn_mfma_i32_16x16x64_i8(pf0, vfr[j], oacc0[j], 0, 0, 0);
      oacc1[j] = __builtin_amdgcn_mfma_i32_16x16x64_i8(pf1, vfr[j], oacc1[j], 0, 0, 0);
    }
#pragma unroll
    for (int q4 = 0; q4 < 4; q4++) { kfr[q4] = kfn[q4]; vfr[q4] = vfn[q4]; }
  }
  {  // chunk 9: ct=36 (only col 576 valid); kf/vf already prefetched
    i32x4 sc0 = __builtin_amdgcn_mfma_i32_16x16x64_i8(kfr[0], qf0, zero, 0, 0, 0);
    i32x4 sc1 = __builtin_amdgcn_mfma_i32_16x16x64_i8(kfr[0], qf1, zero, 0, 0, 0);
    float s0 = (lg == 0) ? (float)sc0[0] * qk2 : -INFINITY;
    float s1 = (lg == 0) ? (float)sc1[0] * qk2 : -INFINITY;
    unsigned pw0[4] = {0u, 0u, 0u, 0u}, pw1[4] = {0u, 0u, 0u, 0u};
    pw0[0] = (unsigned)(int)fminf(rintf(fexp2(s0 + crow0)), 127.0f);
    pw1[0] = (unsigned)(int)fminf(rintf(fexp2(s1 + crow1)), 127.0f);
    i32x4 pf0 = lane_group_transpose(pw0, lg);
    i32x4 pf1 = lane_group_transpose(pw1, lg);
#pragma unroll
    for (int j = 0; j < 4; j++) {
      oacc0[j] = __builtin_amdgcn_mfma_i32_16x16x64_i8(pf0, vfr[j], oacc0[j], 0, 0, 0);
      oacc1[j] = __builtin_amdgcn_mfma_i32_16x16x64_i8(pf1, vfr[j], oacc1[j], 0, 0, 0);
    }
  }

  const float osc = sp * sv;
  float lmax = 0.0f;
#pragma unroll
  for (int j = 0; j < 4; j++) {
    int d = j * 16 + l15;
#pragma unroll
    for (int r = 0; r < 4; r++) {
      int n0g = ntile * 64 + w * 32 + lg * 4 + r;
      if (n0g < N_) {
        float v = (float)oacc0[j][r] * osc;
        score[(size_t)(b * N_ + n0g) * C_ + h * D_ + d] = v;
        lmax = fmaxf(lmax, fabsf(v));
      }
      int n1g = n0g + 16;
      if (n1g < N_) {
        float v = (float)oacc1[j][r] * osc;
        score[(size_t)(b * N_ + n1g) * C_ + h * D_ + d] = v;
        lmax = fmaxf(lmax, fabsf(v));
      }
    }
  }
#pragma unroll
  for (int off = 32; off; off >>= 1) lmax = fmaxf(lmax, __shfl_xor(lmax, off));
  __shared__ float rb[2];
  if (l == 0) rb[w] = lmax;
  __syncthreads();
  if (t == 0) {
    atomicMax(amax_slot, __float_as_uint(fmaxf(rb[0], rb[1])));
  }
}

// ---------------- host launcher ----------------
extern "C" void kernel_launch(void* const* d_in, const int* in_sizes, int n_in,
                              void* d_out, int out_size, void* d_ws, size_t ws_size,
                              hipStream_t stream) {
  const float* x     = (const float*)d_in[0];
  const float* qkvw  = (const float*)d_in[1];
  const float* qkvb  = (const float*)d_in[2];
  const float* projw = (const float*)d_in[3];
  const float* projb = (const float*)d_in[4];
  float* out = (float*)d_out;

  char* ws = (char*)d_ws;
  size_t off = 0;
  auto alloc = [&](size_t bytes) {
    char* p = ws + off;
    off += (bytes + 255) & ~(size_t)255;
    return p;
  };
  float*  scal  = (float*)alloc(64);
  int8_t* x_i8  = (int8_t*)alloc((size_t)BN_ * C_);
  int8_t* w_i8  = (int8_t*)alloc((size_t)O3_ * C_);
  int8_t* pw_i8 = (int8_t*)alloc((size_t)C_ * C_);
  float*  qkv   = (float*)alloc((size_t)BN_ * O3_ * 4);
  int8_t* q_i8  = (int8_t*)alloc((size_t)BH_ * NP_ * D_);
  int8_t* k_i8  = (int8_t*)alloc((size_t)BH_ * NP_ * D_);
  int8_t* vT_i8 = (int8_t*)alloc((size_t)BH_ * D_ * NP_ + 64);
  float*  mbuf  = (float*)alloc((size_t)BH_ * NP_ * 4);
  float*  zbuf  = (float*)alloc((size_t)BH_ * NP_ * 4);
  float*  score = qkv;    // alias: qkv_f32 dead after quant_qkv_k
  int8_t* sc_i8 = x_i8;   // alias: x_i8 dead after gemm1
  unsigned* uscal = (unsigned*)scal;

  const long nx4 = (long)BN_ * C_ / 4, nw4 = (long)O3_ * C_ / 4, npw4 = (long)C_ * C_ / 4;

  init_scal_k<<<1, 64, 0, stream>>>(scal);
  absmax3_k<<<dim3(768, 3), 256, 0, stream>>>((const float4*)x, nx4,
                                              (const float4*)qkvw, nw4,
                                              (const float4*)projw, npw4, uscal);
  quant3_k<<<dim3(768, 3), 256, 0, stream>>>((const float4*)x, (char4*)x_i8, nx4,
                                             (const float4*)qkvw, (char4*)w_i8, nw4,
                                             (const float4*)projw, (char4*)pw_i8, npw4,
                                             scal);
  gemm_i8_nt<0><<<37 * 18, 512, 0, stream>>>(x_i8, w_i8, qkvb, qkv,
                                             scal, 0, 1, BN_, O3_, 18, uscal + 3);
  quant_qkv_k<<<dim3(NT_, BH_), 256, 0, stream>>>(qkv, q_i8, k_i8, vT_i8, scal);
  attn_passA<<<NT_ * BH_, 128, 0, stream>>>(q_i8, k_i8, mbuf, zbuf, scal, uscal + 6);
  attn_passB<<<NT_ * BH_, 128, 0, stream>>>(q_i8, k_i8, vT_i8, mbuf, zbuf, scal,
                                            score, uscal + 7);
  quant_k<<<2048, 256, 0, stream>>>((const float4*)score, (char4*)sc_i8, nx4, scal, 7);
  gemm_i8_nt<1><<<37 * 6, 512, 0, stream>>>(sc_i8, pw_i8, projb, out,
                                            scal, 7, 2, BN_, C_, 6, nullptr);
}

// Round 17
// 179.659 us; speedup vs baseline: 1.0998x; 1.0998x over previous
//
#include <hip/hip_runtime.h>
#include <stdint.h>

typedef int i32x4 __attribute__((ext_vector_type(4)));

#define B_ 16
#define N_ 577
#define C_ 768
#define H_ 12
#define D_ 64
#define BN_ (B_ * N_)   // 9232
#define O3_ (3 * C_)    // 2304
#define NP_ 592         // padded seq length (37*16)
#define BH_ (B_ * H_)   // 192
#define NT_ 10          // 64-row tiles per head (quant_qkv)
#define NT2_ 5          // 128-row q tiles per head (attention)
#define KT_ 12          // K=768 -> 12 K-steps of 64

typedef __attribute__((address_space(1))) const void gvoid;
typedef __attribute__((address_space(3))) void lvoid;

__device__ __forceinline__ void gload16(const void* g, void* l) {
  __builtin_amdgcn_global_load_lds((gvoid*)g, (lvoid*)l, 16, 0, 0);
}

__device__ __forceinline__ float fexp2(float x) {
  float r;
  asm("v_exp_f32 %0, %1" : "=v"(r) : "v"(x));
  return r;
}

__device__ __forceinline__ int8_t quant8(float x, float s) {
  float r = rintf(x / s);               // RNE + true divide: matches jnp exactly
  r = fminf(127.0f, fmaxf(-127.0f, r));
  return (int8_t)(int)r;
}

__device__ __forceinline__ float scale_from(const float* scal, int idx, float pre) {
  return fmaxf(pre * scal[idx] / 127.0f, 1e-8f);
}

// bijective XCD-contiguous swizzle (m204)
__device__ __forceinline__ int xcd_contig(int bid, int nwg) {
  int q = nwg >> 3, r = nwg & 7;
  int xcd = bid & 7, idx = bid >> 3;
  return xcd < r ? xcd * (q + 1) + idx : r * (q + 1) + (xcd - r) * q + idx;
}

// 4x4 lane-group transpose via shfl_xor butterfly (verified all 16 cells):
//   out pf[j]@group g == in pw[g]@group j   (same movement as the LDS round-trip)
__device__ __forceinline__ i32x4 lane_group_transpose(const unsigned pw[4], int lg) {
  unsigned u[4];
#pragma unroll
  for (int j = 0; j < 4; j++) {
    unsigned other = (unsigned)__shfl_xor((int)pw[j ^ 1], 16);
    u[j] = ((j ^ lg) & 1) ? other : pw[j];
  }
  i32x4 pf;
#pragma unroll
  for (int j = 0; j < 4; j++) {
    unsigned other = (unsigned)__shfl_xor((int)u[j ^ 2], 32);
    pf[j] = (int)(((j ^ lg) & 2) ? other : u[j]);
  }
  return pf;
}

// ---------------- init scalar slots ----------------
// [0]=amax_x [1]=amax_qkvw [2]=amax_projw [3]=amax_q_raw [4]=amax_k [5]=amax_v
// [6]=minZ (init +inf) [7]=amax_score
__global__ void init_scal_k(float* scal) {
  int t = threadIdx.x;
  if (t < 16) scal[t] = (t == 6) ? INFINITY : 0.0f;
}

// ---------------- fused absmax over 3 tensors ----------------
__global__ __launch_bounds__(256) void absmax3_k(
    const float4* __restrict__ p0, long n0, const float4* __restrict__ p1, long n1,
    const float4* __restrict__ p2, long n2, unsigned* __restrict__ slots) {
  const int sidx = blockIdx.y;
  const float4* p;
  long n4;
  if (sidx == 0) { p = p0; n4 = n0; }
  else if (sidx == 1) { p = p1; n4 = n1; }
  else { p = p2; n4 = n2; }
  float m = 0.0f;
  long stride = (long)gridDim.x * 256;
  for (long i = (long)blockIdx.x * 256 + threadIdx.x; i < n4; i += stride) {
    float4 v = p[i];
    m = fmaxf(m, fmaxf(fmaxf(fabsf(v.x), fabsf(v.y)), fmaxf(fabsf(v.z), fabsf(v.w))));
  }
#pragma unroll
  for (int off = 32; off; off >>= 1) m = fmaxf(m, __shfl_xor(m, off));
  __shared__ float rb[4];
  if ((threadIdx.x & 63) == 0) rb[threadIdx.x >> 6] = m;
  __syncthreads();
  if (threadIdx.x == 0) {
    m = fmaxf(fmaxf(rb[0], rb[1]), fmaxf(rb[2], rb[3]));
    atomicMax(slots + sidx, __float_as_uint(m));  // float>=0: uint order == float order
  }
}

// ---------------- fused quantize of 3 tensors ----------------
__global__ __launch_bounds__(256) void quant3_k(
    const float4* __restrict__ i0, char4* __restrict__ o0, long n0,
    const float4* __restrict__ i1, char4* __restrict__ o1, long n1,
    const float4* __restrict__ i2, char4* __restrict__ o2, long n2,
    const float* __restrict__ scal) {
  const int sidx = blockIdx.y;
  const float4* in;
  char4* out;
  long n4;
  if (sidx == 0) { in = i0; out = o0; n4 = n0; }
  else if (sidx == 1) { in = i1; out = o1; n4 = n1; }
  else { in = i2; out = o2; n4 = n2; }
  float s = scale_from(scal, sidx, 1.0f);
  long stride = (long)gridDim.x * 256;
  for (long i = (long)blockIdx.x * 256 + threadIdx.x; i < n4; i += stride) {
    float4 v = in[i];
    char4 c;
    c.x = quant8(v.x, s); c.y = quant8(v.y, s);
    c.z = quant8(v.z, s); c.w = quant8(v.w, s);
    out[i] = c;
  }
}

// ---------------- generic quantize (score) ----------------
__global__ __launch_bounds__(256) void quant_k(const float4* __restrict__ in,
                                               char4* __restrict__ out, long n4,
                                               const float* __restrict__ scal, int sidx) {
  float s = scale_from(scal, sidx, 1.0f);
  long stride = (long)gridDim.x * 256;
  for (long i = (long)blockIdx.x * 256 + threadIdx.x; i < n4; i += stride) {
    float4 v = in[i];
    char4 c;
    c.x = quant8(v.x, s); c.y = quant8(v.y, s);
    c.z = quant8(v.z, s); c.w = quant8(v.w, s);
    out[i] = c;
  }
}

// ---------------- int8 NT GEMM: C[M,N] = deq(A[M,K] @ B[N,K]^T) + bias ----------------
// 256x128 tile, 8 waves, 3-slot LDS ring, depth-2 prefetch, counted vmcnt(3),
// setprio; LDS-coalesced f32 epilogue (R12 structure, unchanged).
// MODE 0: qkv  — write C f32 + per-part (q/k/v) absmax
// MODE 1: proj — write C f32
template <int MODE>
__global__ __launch_bounds__(512) void gemm_i8_nt(
    const int8_t* __restrict__ A, const int8_t* __restrict__ Bm,
    const float* __restrict__ bias, float* __restrict__ Cc,
    const float* __restrict__ scal, int sa_idx, int sb_idx,
    int M, int N, int nyb, unsigned* __restrict__ amax_slots) {
  const int K = 768;
  __shared__ __align__(16) int8_t smem[73728];  // 3x16KB A-ring + 3x8KB B-ring
  const int t = threadIdx.x;
  const int l = t & 63, w = t >> 6;          // 8 waves
  const int wm = w >> 1, wn = w & 1;         // 4x2 wave grid -> 256x128
  const int l15 = l & 15, lg = l >> 4;
  const int lin = xcd_contig(blockIdx.x, gridDim.x);
  const int m0 = (lin / nyb) * 256, n0 = (lin % nyb) * 128;

  const int row0 = t >> 2, slot = t & 3;     // rows 0..127, 16B slot
  int ar0 = m0 + row0;        if (ar0 >= M) ar0 = M - 1;
  int ar1 = m0 + 128 + row0;  if (ar1 >= M) ar1 = M - 1;
  const int8_t* gA0 = A + (size_t)ar0 * K + slot * 16;
  const int8_t* gA1 = A + (size_t)ar1 * K + slot * 16;
  const int8_t* gB0 = Bm + (size_t)(n0 + row0) * K + slot * 16;

  auto stage = [&](int buf, int k0) {
    int8_t* la = smem + buf * 16384 + w * 1024;
    int8_t* lb = smem + 49152 + buf * 8192 + w * 1024;
    gload16(gA0 + k0, la);
    gload16(gA1 + k0, la + 8192);
    gload16(gB0 + k0, lb);
  };

  i32x4 zero = {0, 0, 0, 0};
  i32x4 acc[4][4];
#pragma unroll
  for (int i = 0; i < 4; i++)
#pragma unroll
    for (int j = 0; j < 4; j++) acc[i][j] = zero;

  stage(0, 0);
  stage(1, 64);

#pragma unroll
  for (int kt = 0; kt < KT_; kt++) {
    if (kt < KT_ - 1) asm volatile("s_waitcnt vmcnt(3)" ::: "memory");
    else              asm volatile("s_waitcnt vmcnt(0)" ::: "memory");
    __builtin_amdgcn_s_barrier();
    __builtin_amdgcn_sched_barrier(0);  // pin stage/ds_read below the barrier
    if (kt + 2 < KT_) stage((kt + 2) % 3, (kt + 2) * 64);
    const int8_t* as_ = smem + (kt % 3) * 16384;
    const int8_t* bs_ = smem + 49152 + (kt % 3) * 8192;
    i32x4 af[4], bf[4];
#pragma unroll
    for (int i = 0; i < 4; i++)
      af[i] = *(const i32x4*)(as_ + (wm * 64 + i * 16 + l15) * 64 + lg * 16);
#pragma unroll
    for (int j = 0; j < 4; j++)
      bf[j] = *(const i32x4*)(bs_ + (wn * 64 + j * 16 + l15) * 64 + lg * 16);
    __builtin_amdgcn_s_setprio(1);
#pragma unroll
    for (int i = 0; i < 4; i++)
#pragma unroll
      for (int j = 0; j < 4; j++)
        acc[i][j] = __builtin_amdgcn_mfma_i32_16x16x64_i8(af[i], bf[j], acc[i][j], 0, 0, 0);
    __builtin_amdgcn_s_setprio(0);
    asm volatile("s_waitcnt lgkmcnt(0)" ::: "memory");
    __builtin_amdgcn_sched_barrier(0);
  }

  const float ab = scale_from(scal, sa_idx, 1.0f) * scale_from(scal, sb_idx, 1.0f);
  float lmax = 0.0f;
  float* eplds = (float*)smem;  // epilogue tile: 128 rows x 132 f32 (pad)
#pragma unroll
  for (int h = 0; h < 2; h++) {
    __syncthreads();  // staging reads (h=0) / prior stores (h=1) done
    if ((wm >> 1) == h) {
      const int lrbase = (wm & 1) * 64;
#pragma unroll
      for (int i = 0; i < 4; i++) {
#pragma unroll
        for (int j = 0; j < 4; j++) {
          int lc = wn * 64 + j * 16 + l15;
          float bv = bias[n0 + lc];
#pragma unroll
          for (int r = 0; r < 4; r++) {
            int lr = lrbase + i * 16 + lg * 4 + r;
            float v = (float)acc[i][j][r] * ab + bv;
            eplds[lr * 132 + lc] = v;
            if (MODE == 0) {
              if (m0 + h * 128 + lr < M) lmax = fmaxf(lmax, fabsf(v));
            }
          }
        }
      }
    }
    __syncthreads();
#pragma unroll
    for (int it = 0; it < 8; it++) {
      int e = it * 512 + t;
      int row = e >> 5, c4 = e & 31;
      int grow = m0 + h * 128 + row;
      if (grow < M)
        *(float4*)(Cc + (size_t)grow * N + n0 + c4 * 4) =
            *(const float4*)(eplds + row * 132 + c4 * 4);
    }
  }
  if (MODE == 0) {
#pragma unroll
    for (int off = 32; off; off >>= 1) lmax = fmaxf(lmax, __shfl_xor(lmax, off));
    __shared__ float rb[8];
    if (l == 0) rb[w] = lmax;
    __syncthreads();
    if (t == 0) {
      float v = fmaxf(fmaxf(fmaxf(rb[0], rb[1]), fmaxf(rb[2], rb[3])),
                      fmaxf(fmaxf(rb[4], rb[5]), fmaxf(rb[6], rb[7])));
      atomicMax(amax_slots + (n0 / 768), __float_as_uint(v));
    }
  }
}

// ---------------- quantize qkv -> q_i8, k_i8, vT_i8 ----------------
__global__ __launch_bounds__(256) void quant_qkv_k(
    const float* __restrict__ qkv, int8_t* __restrict__ qq,
    int8_t* __restrict__ kq, int8_t* __restrict__ vT,
    const float* __restrict__ scal) {
  const int ntile = blockIdx.x, bh = blockIdx.y;
  const int b = bh / H_, h = bh % H_;
  const int t = threadIdx.x;
  const float sq = scale_from(scal, 3, 0.125f);  // q pre-scaled by D^-0.5
  const float sk = scale_from(scal, 4, 1.0f);
  const float sv = scale_from(scal, 5, 1.0f);
  __shared__ int8_t vt[64 * 68];
  const int n0 = ntile * 64;
#pragma unroll
  for (int i = 0; i < 4; i++) {
    int e = i * 256 + t;          // 0..1023 = 64 rows x 16 float4
    int nl = e >> 4, d4 = e & 15;
    int n = n0 + nl;
    float4 qv = {0, 0, 0, 0}, kv = {0, 0, 0, 0}, vv = {0, 0, 0, 0};
    if (n < N_) {
      const float* base = qkv + (size_t)(b * N_ + n) * O3_ + h * D_ + d4 * 4;
      qv = *(const float4*)(base);
      kv = *(const float4*)(base + C_);
      vv = *(const float4*)(base + 2 * C_);
    }
    char4 qb, kb, vb;
    qb.x = quant8(0.125f * qv.x, sq); qb.y = quant8(0.125f * qv.y, sq);
    qb.z = quant8(0.125f * qv.z, sq); qb.w = quant8(0.125f * qv.w, sq);
    kb.x = quant8(kv.x, sk); kb.y = quant8(kv.y, sk);
    kb.z = quant8(kv.z, sk); kb.w = quant8(kv.w, sk);
    vb.x = quant8(vv.x, sv); vb.y = quant8(vv.y, sv);
    vb.z = quant8(vv.z, sv); vb.w = quant8(vv.w, sv);
    if (n < NP_) {
      size_t o = (size_t)(bh * NP_ + n) * D_ + d4 * 4;
      *(char4*)(qq + o) = qb;
      *(char4*)(kq + o) = kb;
    }
    *(char4*)(vt + nl * 68 + d4 * 4) = vb;
  }
  __syncthreads();
#pragma unroll
  for (int i = 0; i < 16; i++) {
    int e = i * 256 + t;
    int dr = e >> 6, nn = e & 63;
    int n = n0 + nn;
    if (n < NP_) vT[(size_t)(bh * 64 + dr) * NP_ + n] = vt[nn * 68 + dr];
  }
}

// ---------------- attention pass A: per-row (max, Z) in exp2 domain ----------------
// 2 q-fragments per wave (32 rows): kf loads shared, 2x MFMA per ct (R13).
__global__ __launch_bounds__(256) void attn_passA(
    const int8_t* __restrict__ qq, const int8_t* __restrict__ kq,
    float* __restrict__ mbuf, float* __restrict__ zbuf,
    const float* __restrict__ scal, unsigned* __restrict__ minz_slot) {
  const int lin = xcd_contig(blockIdx.x, gridDim.x);
  const int bh = lin / NT2_, ntile = lin % NT2_;
  const int t = threadIdx.x;
  const int l = t & 63, w = t >> 6;
  const int l15 = l & 15, lg = l >> 4;
  const float qk2 =
      scale_from(scal, 3, 0.125f) * scale_from(scal, 4, 1.0f) * 1.4426950408889634f;
  const int nrow0 = ntile * 128 + w * 32 + l15;
  const int nrow1 = nrow0 + 16;
  const int nc0 = nrow0 < NP_ ? nrow0 : 0;
  const int nc1 = nrow1 < NP_ ? nrow1 : 0;
  const i32x4 qf0 = *(const i32x4*)(qq + ((size_t)bh * NP_ + nc0) * 64 + lg * 16);
  const i32x4 qf1 = *(const i32x4*)(qq + ((size_t)bh * NP_ + nc1) * 64 + lg * 16);
  const int8_t* kb = kq + (size_t)bh * NP_ * 64;

  i32x4 zero = {0, 0, 0, 0};
  i32x4 k0 = *(const i32x4*)(kb + (0 * 16 + l15) * 64 + lg * 16);
  i32x4 k1 = *(const i32x4*)(kb + (1 * 16 + l15) * 64 + lg * 16);
  i32x4 k2 = *(const i32x4*)(kb + (2 * 16 + l15) * 64 + lg * 16);
  i32x4 k3 = *(const i32x4*)(kb + (3 * 16 + l15) * 64 + lg * 16);

  float m2a = -INFINITY, zla = 0.0f, m2b = -INFINITY, zlb = 0.0f;
#pragma unroll
  for (int ct = 0; ct < 36; ct++) {
    i32x4 kfc = k0;
    k0 = k1; k1 = k2; k2 = k3;
    if (ct + 4 <= 36)
      k3 = *(const i32x4*)(kb + ((ct + 4) * 16 + l15) * 64 + lg * 16);
    i32x4 sc0 = __builtin_amdgcn_mfma_i32_16x16x64_i8(kfc, qf0, zero, 0, 0, 0);
    i32x4 sc1 = __builtin_amdgcn_mfma_i32_16x16x64_i8(kfc, qf1, zero, 0, 0, 0);
    {
      float s0 = (float)sc0[0] * qk2, s1 = (float)sc0[1] * qk2;
      float s2 = (float)sc0[2] * qk2, s3 = (float)sc0[3] * qk2;
      float m4 = fmaxf(fmaxf(s0, s1), fmaxf(s2, s3));
      float nm = fmaxf(m2a, m4);
      zla = zla * fexp2(m2a - nm) +
            ((fexp2(s0 - nm) + fexp2(s1 - nm)) + (fexp2(s2 - nm) + fexp2(s3 - nm)));
      m2a = nm;
    }
    {
      float s0 = (float)sc1[0] * qk2, s1 = (float)sc1[1] * qk2;
      float s2 = (float)sc1[2] * qk2, s3 = (float)sc1[3] * qk2;
      float m4 = fmaxf(fmaxf(s0, s1), fmaxf(s2, s3));
      float nm = fmaxf(m2b, m4);
      zlb = zlb * fexp2(m2b - nm) +
            ((fexp2(s0 - nm) + fexp2(s1 - nm)) + (fexp2(s2 - nm) + fexp2(s3 - nm)));
      m2b = nm;
    }
  }
  {  // ct=36 (in k0 after rotation): only col 576 valid (lg==0 && r==0)
    i32x4 sc0 = __builtin_amdgcn_mfma_i32_16x16x64_i8(k0, qf0, zero, 0, 0, 0);
    i32x4 sc1 = __builtin_amdgcn_mfma_i32_16x16x64_i8(k0, qf1, zero, 0, 0, 0);
    float sa = (lg == 0) ? (float)sc0[0] * qk2 : -INFINITY;
    float sb = (lg == 0) ? (float)sc1[0] * qk2 : -INFINITY;
    float nma = fmaxf(m2a, sa);
    zla = zla * fexp2(m2a - nma) + fexp2(sa - nma);
    m2a = nma;
    float nmb = fmaxf(m2b, sb);
    zlb = zlb * fexp2(m2b - nmb) + fexp2(sb - nmb);
    m2b = nmb;
  }
#pragma unroll
  for (int off = 16; off <= 32; off <<= 1) {
    float om = __shfl_xor(m2a, off), ol = __shfl_xor(zla, off);
    float nm = fmaxf(m2a, om);
    zla = zla * fexp2(m2a - nm) + ol * fexp2(om - nm);
    m2a = nm;
    om = __shfl_xor(m2b, off); ol = __shfl_xor(zlb, off);
    nm = fmaxf(m2b, om);
    zlb = zlb * fexp2(m2b - nm) + ol * fexp2(om - nm);
    m2b = nm;
  }
  const bool rv0 = nrow0 < N_, rv1 = nrow1 < N_;
  if (lg == 0) {
    if (rv0) {
      mbuf[(size_t)bh * NP_ + nrow0] = m2a;
      zbuf[(size_t)bh * NP_ + nrow0] = zla;
    }
    if (rv1) {
      mbuf[(size_t)bh * NP_ + nrow1] = m2b;
      zbuf[(size_t)bh * NP_ + nrow1] = zlb;
    }
  }
  float cand = INFINITY;
  if (lg == 0) {
    if (rv0) cand = zla;
    if (rv1) cand = fminf(cand, zlb);
  }
#pragma unroll
  for (int off = 32; off; off >>= 1) cand = fminf(cand, __shfl_xor(cand, off));
  __shared__ float rb[4];
  if (l == 0) rb[w] = cand;
  __syncthreads();
  if (t == 0)
    atomicMin(minz_slot, __float_as_uint(fminf(fminf(rb[0], rb[1]), fminf(rb[2], rb[3]))));
}

// ---------------- attention pass B: p = fq(softmax), score = deq(p @ v) ----------------
// 2 q-fragments per wave (32 rows): kf/vf loads shared, 2x QK + 2x PV MFMA per
// chunk. Register-pipelined kf prefetch + in-register transpose (R13).
__global__ __launch_bounds__(256) void attn_passB(
    const int8_t* __restrict__ qq, const int8_t* __restrict__ kq,
    const int8_t* __restrict__ vT, const float* __restrict__ mbuf,
    const float* __restrict__ zbuf, const float* __restrict__ scal,
    float* __restrict__ score, unsigned* __restrict__ amax_slot) {
  const int lin = xcd_contig(blockIdx.x, gridDim.x);
  const int bh = lin / NT2_, ntile = lin % NT2_;
  const int b = bh / H_, h = bh % H_;
  const int t = threadIdx.x;
  const int l = t & 63, w = t >> 6;
  const int l15 = l & 15, lg = l >> 4;
  const int8_t* kb = kq + (size_t)bh * NP_ * 64;
  const int8_t* vbase = vT + (size_t)bh * 64 * NP_;

  const float qk2 =
      scale_from(scal, 3, 0.125f) * scale_from(scal, 4, 1.0f) * 1.4426950408889634f;
  const float sv = scale_from(scal, 5, 1.0f);
  const float minz = scal[6];
  const float sp = fmaxf((1.0f / minz) / 127.0f, 1e-8f);  // amax(softmax) = 1/minZ

  const int nrow0 = ntile * 128 + w * 32 + l15;
  const int nrow1 = nrow0 + 16;
  const int nc0 = nrow0 < NP_ ? nrow0 : 0;
  const int nc1 = nrow1 < NP_ ? nrow1 : 0;
  const i32x4 qf0 = *(const i32x4*)(qq + ((size_t)bh * NP_ + nc0) * 64 + lg * 16);
  const i32x4 qf1 = *(const i32x4*)(qq + ((size_t)bh * NP_ + nc1) * 64 + lg * 16);
  float crow0 = -INFINITY, crow1 = -INFINITY;
  if (nrow0 < N_)
    crow0 = -mbuf[(size_t)bh * NP_ + nrow0] - log2f(zbuf[(size_t)bh * NP_ + nrow0] * sp);
  if (nrow1 < N_)
    crow1 = -mbuf[(size_t)bh * NP_ + nrow1] - log2f(zbuf[(size_t)bh * NP_ + nrow1] * sp);

  i32x4 zero = {0, 0, 0, 0};
  i32x4 oacc0[4], oacc1[4];
#pragma unroll
  for (int j = 0; j < 4; j++) { oacc0[j] = zero; oacc1[j] = zero; }

  i32x4 kfr[4], vfr[4], vtl[4];
#pragma unroll
  for (int q4 = 0; q4 < 4; q4++)
    kfr[q4] = *(const i32x4*)(kb + (q4 * 16 + l15) * 64 + lg * 16);

#pragma unroll
  for (int chunk = 0; chunk < 9; chunk++) {
    // vf for THIS chunk (shared by both q-groups; consumed after softmax)
#pragma unroll
    for (int j = 0; j < 4; j++)
      vfr[j] = *(const i32x4*)(vbase + (size_t)(j * 16 + l15) * NP_ + chunk * 64 + lg * 16);
    // kf prefetch for NEXT chunk (or tail)
    i32x4 kfn[4];
    if (chunk < 8) {
#pragma unroll
      for (int q4 = 0; q4 < 4; q4++)
        kfn[q4] = *(const i32x4*)(kb + (((chunk + 1) * 4 + q4) * 16 + l15) * 64 + lg * 16);
    } else {
      kfn[0] = *(const i32x4*)(kb + (36 * 16 + l15) * 64 + lg * 16);
      kfn[1] = zero; kfn[2] = zero; kfn[3] = zero;
#pragma unroll
      for (int j = 0; j < 4; j++)
        vtl[j] = *(const i32x4*)(vbase + (size_t)(j * 16 + l15) * NP_ + 576);
    }
    // QK + softmax + pack for both q-groups (kf already in regs)
    unsigned pw0[4], pw1[4];
#pragma unroll
    for (int q4 = 0; q4 < 4; q4++) {
      i32x4 sc0 = __builtin_amdgcn_mfma_i32_16x16x64_i8(kfr[q4], qf0, zero, 0, 0, 0);
      i32x4 sc1 = __builtin_amdgcn_mfma_i32_16x16x64_i8(kfr[q4], qf1, zero, 0, 0, 0);
      unsigned w0 = 0, w1 = 0;
#pragma unroll
      for (int r = 0; r < 4; r++) {
        float s0 = (float)sc0[r] * qk2;
        float r0 = fminf(rintf(fexp2(s0 + crow0)), 127.0f);
        w0 |= ((unsigned)(int)r0) << (r * 8);
        float s1 = (float)sc1[r] * qk2;
        float r1 = fminf(rintf(fexp2(s1 + crow1)), 127.0f);
        w1 |= ((unsigned)(int)r1) << (r * 8);
      }
      pw0[q4] = w0; pw1[q4] = w1;
    }
    i32x4 pf0 = lane_group_transpose(pw0, lg);
    i32x4 pf1 = lane_group_transpose(pw1, lg);
#pragma unroll
    for (int j = 0; j < 4; j++) {
      oacc0[j] = __builtin_amdgcn_mfma_i32_16x16x64_i8(pf0, vfr[j], oacc0[j], 0, 0, 0);
      oacc1[j] = __builtin_amdgcn_mfma_i32_16x16x64_i8(pf1, vfr[j], oacc1[j], 0, 0, 0);
    }
#pragma unroll
    for (int q4 = 0; q4 < 4; q4++) kfr[q4] = kfn[q4];
  }
  {  // chunk 9: ct=36 (only col 576 valid); kf/vf already prefetched
    i32x4 sc0 = __builtin_amdgcn_mfma_i32_16x16x64_i8(kfr[0], qf0, zero, 0, 0, 0);
    i32x4 sc1 = __builtin_amdgcn_mfma_i32_16x16x64_i8(kfr[0], qf1, zero, 0, 0, 0);
    float s0 = (lg == 0) ? (float)sc0[0] * qk2 : -INFINITY;
    float s1 = (lg == 0) ? (float)sc1[0] * qk2 : -INFINITY;
    unsigned pw0[4] = {0u, 0u, 0u, 0u}, pw1[4] = {0u, 0u, 0u, 0u};
    pw0[0] = (unsigned)(int)fminf(rintf(fexp2(s0 + crow0)), 127.0f);
    pw1[0] = (unsigned)(int)fminf(rintf(fexp2(s1 + crow1)), 127.0f);
    i32x4 pf0 = lane_group_transpose(pw0, lg);
    i32x4 pf1 = lane_group_transpose(pw1, lg);
#pragma unroll
    for (int j = 0; j < 4; j++) {
      oacc0[j] = __builtin_amdgcn_mfma_i32_16x16x64_i8(pf0, vtl[j], oacc0[j], 0, 0, 0);
      oacc1[j] = __builtin_amdgcn_mfma_i32_16x16x64_i8(pf1, vtl[j], oacc1[j], 0, 0, 0);
    }
  }

  const float osc = sp * sv;
  float lmax = 0.0f;
#pragma unroll
  for (int j = 0; j < 4; j++) {
    int d = j * 16 + l15;
#pragma unroll
    for (int r = 0; r < 4; r++) {
      int n0g = ntile * 128 + w * 32 + lg * 4 + r;
      if (n0g < N_) {
        float v = (float)oacc0[j][r] * osc;
        score[(size_t)(b * N_ + n0g) * C_ + h * D_ + d] = v;
        lmax = fmaxf(lmax, fabsf(v));
      }
      int n1g = n0g + 16;
      if (n1g < N_) {
        float v = (float)oacc1[j][r] * osc;
        score[(size_t)(b * N_ + n1g) * C_ + h * D_ + d] = v;
        lmax = fmaxf(lmax, fabsf(v));
      }
    }
  }
#pragma unroll
  for (int off = 32; off; off >>= 1) lmax = fmaxf(lmax, __shfl_xor(lmax, off));
  __shared__ float rb[4];
  if (l == 0) rb[w] = lmax;
  __syncthreads();
  if (t == 0) {
    float v = fmaxf(fmaxf(rb[0], rb[1]), fmaxf(rb[2], rb[3]));
    atomicMax(amax_slot, __float_as_uint(v));
  }
}

// ---------------- host launcher ----------------
extern "C" void kernel_launch(void* const* d_in, const int* in_sizes, int n_in,
                              void* d_out, int out_size, void* d_ws, size_t ws_size,
                              hipStream_t stream) {
  const float* x     = (const float*)d_in[0];
  const float* qkvw  = (const float*)d_in[1];
  const float* qkvb  = (const float*)d_in[2];
  const float* projw = (const float*)d_in[3];
  const float* projb = (const float*)d_in[4];
  float* out = (float*)d_out;

  char* ws = (char*)d_ws;
  size_t off = 0;
  auto alloc = [&](size_t bytes) {
    char* p = ws + off;
    off += (bytes + 255) & ~(size_t)255;
    return p;
  };
  float*  scal  = (float*)alloc(64);
  int8_t* x_i8  = (int8_t*)alloc((size_t)BN_ * C_);
  int8_t* w_i8  = (int8_t*)alloc((size_t)O3_ * C_);
  int8_t* pw_i8 = (int8_t*)alloc((size_t)C_ * C_);
  float*  qkv   = (float*)alloc((size_t)BN_ * O3_ * 4);
  int8_t* q_i8  = (int8_t*)alloc((size_t)BH_ * NP_ * D_);
  int8_t* k_i8  = (int8_t*)alloc((size_t)BH_ * NP_ * D_);
  int8_t* vT_i8 = (int8_t*)alloc((size_t)BH_ * D_ * NP_ + 64);
  float*  mbuf  = (float*)alloc((size_t)BH_ * NP_ * 4);
  float*  zbuf  = (float*)alloc((size_t)BH_ * NP_ * 4);
  float*  score = qkv;    // alias: qkv_f32 dead after quant_qkv_k
  int8_t* sc_i8 = x_i8;   // alias: x_i8 dead after gemm1
  unsigned* uscal = (unsigned*)scal;

  const long nx4 = (long)BN_ * C_ / 4, nw4 = (long)O3_ * C_ / 4, npw4 = (long)C_ * C_ / 4;

  init_scal_k<<<1, 64, 0, stream>>>(scal);
  absmax3_k<<<dim3(768, 3), 256, 0, stream>>>((const float4*)x, nx4,
                                              (const float4*)qkvw, nw4,
                                              (const float4*)projw, npw4, uscal);
  quant3_k<<<dim3(768, 3), 256, 0, stream>>>((const float4*)x, (char4*)x_i8, nx4,
                                             (const float4*)qkvw, (char4*)w_i8, nw4,
                                             (const float4*)projw, (char4*)pw_i8, npw4,
                                             scal);
  gemm_i8_nt<0><<<37 * 18, 512, 0, stream>>>(x_i8, w_i8, qkvb, qkv,
                                             scal, 0, 1, BN_, O3_, 18, uscal + 3);
  quant_qkv_k<<<dim3(NT_, BH_), 256, 0, stream>>>(qkv, q_i8, k_i8, vT_i8, scal);
  attn_passA<<<NT2_ * BH_, 256, 0, stream>>>(q_i8, k_i8, mbuf, zbuf, scal, uscal + 6);
  attn_passB<<<NT2_ * BH_, 256, 0, stream>>>(q_i8, k_i8, vT_i8, mbuf, zbuf, scal,
                                             score, uscal + 7);
  quant_k<<<2048, 256, 0, stream>>>((const float4*)score, (char4*)sc_i8, nx4, scal, 7);
  gemm_i8_nt<1><<<37 * 6, 512, 0, stream>>>(sc_i8, pw_i8, projb, out,
                                            scal, 7, 2, BN_, C_, 6, nullptr);
}